// Round 4
// baseline (466.726 us; speedup 1.0000x reference)
//
#include <hip/hip_runtime.h>
#include <hip/hip_bf16.h>
#include <math.h>

// GLA block, MI355X. Round 4: runtime dtype detection (f32 vs bf16 buffers) +
// canonical bf16 conversion of all inputs; verified pipeline unchanged; MFMA
// GEMM restored (proven == scalar in rounds 2/3). Output dtype follows flag.

using bf16 = __hip_bfloat16;
typedef __attribute__((ext_vector_type(8))) short bf16x8;
typedef __attribute__((ext_vector_type(4))) float f32x4;

#define BT 4096
#define HM 1024
#define DK 32
#define DV 64
#define NC 32
#define CHK 64

__device__ __forceinline__ float b2f(bf16 v) { return __bfloat162float(v); }
__device__ __forceinline__ bf16 f2b(float v) { return __float2bfloat16(v); }
__device__ __forceinline__ float clampf(float v, float lim) {
    return fminf(fmaxf(v, -lim), lim);
}
__device__ __forceinline__ float lo16(unsigned int u) {
    union { unsigned int i; float f; } c; c.i = u << 16; return c.f;
}
__device__ __forceinline__ float hi16(unsigned int u) {
    union { unsigned int i; float f; } c; c.i = u & 0xffff0000u; return c.f;
}
__device__ __forceinline__ void acc8(float a, uint4 r, float* o) {
    o[0] += a * lo16(r.x); o[1] += a * hi16(r.x);
    o[2] += a * lo16(r.y); o[3] += a * hi16(r.y);
    o[4] += a * lo16(r.z); o[5] += a * hi16(r.z);
    o[6] += a * lo16(r.w); o[7] += a * hi16(r.w);
}

// ---------------- dtype detector ----------------
// If buffers are bf16: words hold two bf16 values; both exponent fields (bits
// 7-14 and 23-30) land in [110,135] for ~N(0,1)-ish data (~96% of words).
// If f32: bits 7-14 are mantissa junk (~10% in range). Threshold at 50%.
__global__ __launch_bounds__(256) void detect_dtype(
    const unsigned int* __restrict__ x, int* __restrict__ flag)
{
    int tid = threadIdx.x;
    int cnt = 0;
    for (int i = 0; i < 16; ++i) {
        unsigned int w = x[tid * 16 + i];
        unsigned int e_lo = (w >> 7) & 0xffu;
        unsigned int e_hi = (w >> 23) & 0xffu;
        cnt += (e_lo >= 110 && e_lo <= 135 && e_hi >= 110 && e_hi <= 135) ? 1 : 0;
    }
    __shared__ int red[256];
    red[tid] = cnt;
    __syncthreads();
    for (int s = 128; s > 0; s >>= 1) {
        if (tid < s) red[tid] += red[tid + s];
        __syncthreads();
    }
    if (tid == 0) *flag = (red[0] > 2048) ? 1 : 0;  // 1 = bf16 buffers, 0 = f32
}

// ---------------- canonicalize input -> bf16 ----------------
__global__ __launch_bounds__(256) void cvt_to_bf16(
    const void* __restrict__ src, bf16* __restrict__ dst, int n,
    const int* __restrict__ flag)
{
    bool isb = (*flag != 0);
    int i = blockIdx.x * 256 + threadIdx.x;
    int stride = gridDim.x * 256;
    for (; i < n; i += stride) {
        if (isb) ((ushort*)dst)[i] = ((const ushort*)src)[i];
        else     dst[i] = f2b(((const float*)src)[i]);
    }
}

// ---------------- transpose: src[R][C] -> dst[C][R], bf16 ----------------
__global__ __launch_bounds__(256) void transpose_bf16(
    const ushort* __restrict__ src, ushort* __restrict__ dst, int R, int C)
{
    __shared__ ushort tile[32][33];
    int c0 = blockIdx.x * 32, r0 = blockIdx.y * 32;
    int x = threadIdx.x, y = threadIdx.y;  // 32 x 8
    #pragma unroll
    for (int dy = 0; dy < 32; dy += 8)
        tile[y + dy][x] = src[(size_t)(r0 + y + dy) * C + c0 + x];
    __syncthreads();
    #pragma unroll
    for (int dy = 0; dy < 32; dy += 8)
        dst[(size_t)(c0 + y + dy) * R + r0 + x] = tile[x][y + dy];
}

// ---------------- LayerNorm: rows of 1024, out bf16 ----------------
template <typename TI>
__global__ __launch_bounds__(256) void ln_kernel(
    const TI* __restrict__ x, const bf16* __restrict__ w, const bf16* __restrict__ b,
    bf16* __restrict__ out)
{
    size_t base = (size_t)blockIdx.x * HM;
    int tid = threadIdx.x;
    float v[4], s = 0.f, s2 = 0.f;
    #pragma unroll
    for (int u = 0; u < 4; ++u) {
        float f;
        if constexpr (sizeof(TI) == 2) f = b2f(((const bf16*)x)[base + tid + u * 256]);
        else                           f = ((const float*)x)[base + tid + u * 256];
        v[u] = f; s += f; s2 += f * f;
    }
    #pragma unroll
    for (int off = 32; off >= 1; off >>= 1) {
        s  += __shfl_down(s, off);
        s2 += __shfl_down(s2, off);
    }
    __shared__ float ra[4], rb[4];
    int wave = tid >> 6;
    if ((tid & 63) == 0) { ra[wave] = s; rb[wave] = s2; }
    __syncthreads();
    s = ra[0] + ra[1] + ra[2] + ra[3];
    s2 = rb[0] + rb[1] + rb[2] + rb[3];
    float mean = s * (1.f / HM);
    float var = fmaxf(s2 * (1.f / HM) - mean * mean, 0.f);
    float rs = rsqrtf(var + 1e-5f);
    #pragma unroll
    for (int u = 0; u < 4; ++u) {
        int col = tid + u * 256;
        out[base + col] = f2b((v[u] - mean) * rs * b2f(w[col]) + b2f(b[col]));
    }
}

// ---------------- gate low-rank MLP ----------------
__global__ __launch_bounds__(256) void gk_kernel(
    const bf16* __restrict__ h, const bf16* __restrict__ w1,
    const bf16* __restrict__ w2, const bf16* __restrict__ b2i,
    bf16* __restrict__ gkout)
{
    size_t row = blockIdx.x;
    const bf16* hr = h + row * HM;
    int tid = threadIdx.x;
    int d = tid & 15, seg = tid >> 4;
    float s = 0.f;
    for (int j = 0; j < 64; ++j) {
        int i = seg * 64 + j;
        s += b2f(hr[i]) * b2f(w1[i * 16 + d]);
    }
    __shared__ float red[256];
    __shared__ float g1[16];
    red[tid] = s;
    __syncthreads();
    if (tid < 16) {
        float t = 0.f;
        #pragma unroll
        for (int sg = 0; sg < 16; ++sg) t += red[sg * 16 + tid];
        g1[tid] = t;
    }
    __syncthreads();
    #pragma unroll
    for (int rep = 0; rep < 2; ++rep) {
        int n = tid + rep * 256;
        float z = b2f(b2i[n]);
        #pragma unroll
        for (int r = 0; r < 16; ++r) z += g1[r] * b2f(w2[r * 512 + n]);
        z = clampf(z, 30.f);
        float ls = (z >= 0.f) ? -log1pf(expf(-z)) : (z - log1pf(expf(z)));
        gkout[row * 512 + n] = f2b(ls * 0.0625f);
    }
}

// ---------------- MFMA GEMM: C[M,N] = A[M,K] @ Wt[N,K]^T ----------------
// MODE 0: plain -> bf16; 1: f32 = resid_bf16 + acc; 2: bf16 = gelu(acc+bias);
// MODE 3: resid_f32 + acc + bias -> d_out as f32 or bf16 per oflag
template <int MODE>
__global__ __launch_bounds__(256) void gemm_bt(
    const bf16* __restrict__ A, const bf16* __restrict__ Wt,
    const bf16* __restrict__ bias, const void* __restrict__ resid,
    void* __restrict__ out, int M, int N, int K, const int* __restrict__ oflag)
{
    __shared__ __align__(16) ushort As[64][40];
    __shared__ __align__(16) ushort Bs[64][40];
    int tid = threadIdx.x;
    int bm = blockIdx.x * 64, bn = blockIdx.y * 64;
    int wave = tid >> 6, lane = tid & 63;
    int wm = (wave >> 1) * 32, wn = (wave & 1) * 32;
    int row16 = lane & 15, quad = lane >> 4;
    int lr = tid >> 2, lc = (tid & 3) * 8;
    bool out_bf16 = false;
    if constexpr (MODE == 3) out_bf16 = (*oflag != 0);

    f32x4 acc[2][2] = {};
    const ushort* Au = (const ushort*)A;
    const ushort* Wu = (const ushort*)Wt;

    for (int k0 = 0; k0 < K; k0 += 32) {
        __syncthreads();
        *(int4*)&As[lr][lc] = *(const int4*)(Au + (size_t)(bm + lr) * K + k0 + lc);
        *(int4*)&Bs[lr][lc] = *(const int4*)(Wu + (size_t)(bn + lr) * K + k0 + lc);
        __syncthreads();
        #pragma unroll
        for (int mi = 0; mi < 2; ++mi) {
            bf16x8 a = *(const bf16x8*)&As[wm + mi * 16 + row16][quad * 8];
            #pragma unroll
            for (int ni = 0; ni < 2; ++ni) {
                bf16x8 b = *(const bf16x8*)&Bs[wn + ni * 16 + row16][quad * 8];
                acc[mi][ni] = __builtin_amdgcn_mfma_f32_16x16x32_bf16(a, b, acc[mi][ni], 0, 0, 0);
            }
        }
    }
    #pragma unroll
    for (int mi = 0; mi < 2; ++mi) {
        #pragma unroll
        for (int ni = 0; ni < 2; ++ni) {
            int col = bn + wn + ni * 16 + row16;
            #pragma unroll
            for (int r = 0; r < 4; ++r) {
                int row = bm + wm + mi * 16 + quad * 4 + r;
                size_t idx = (size_t)row * N + col;
                float v = acc[mi][ni][r];
                if constexpr (MODE == 0) {
                    ((bf16*)out)[idx] = f2b(clampf(v, 1e4f));
                } else if constexpr (MODE == 1) {
                    ((float*)out)[idx] = clampf(b2f(((const bf16*)resid)[idx]) + v, 1e5f);
                } else if constexpr (MODE == 2) {
                    float t = clampf(v + b2f(bias[col]), 50.f);
                    ((bf16*)out)[idx] = f2b(0.5f * t * (1.f + erff(t * 0.70710678f)));
                } else {
                    float t = clampf(v + b2f(bias[col]) + ((const float*)resid)[idx], 2e5f);
                    if (out_bf16) ((bf16*)out)[idx] = f2b(t);
                    else          ((float*)out)[idx] = t;
                }
            }
        }
    }
}

// ---------------- GLA phase 1 ----------------
__global__ __launch_bounds__(256) void gla_phase1(
    const bf16* __restrict__ gkb, const bf16* __restrict__ qk,
    const bf16* __restrict__ vg,
    float* __restrict__ clbuf, float* __restrict__ Dbuf, float* __restrict__ Pbuf)
{
    int bh = blockIdx.x, c = blockIdx.y;
    int b = bh >> 4, hh = bh & 15;
    int row0 = b * 2048 + c * CHK;
    __shared__ float glog[CHK][DK];
    __shared__ float wk[CHK][DK];
    __shared__ __align__(16) ushort vt[CHK][DV];
    int tid = threadIdx.x;
    int i = tid >> 2, k8 = (tid & 3) * 8;
    #pragma unroll
    for (int u = 0; u < 8; ++u) {
        float g = b2f(gkb[(size_t)(row0 + i) * 512 + hh * 32 + k8 + u]);
        glog[i][k8 + u] = fminf(fmaxf(g, -2.f), 0.f);
    }
    {
        int v16 = (tid & 3) * 16;
        #pragma unroll
        for (int u = 0; u < 16; ++u)
            vt[i][v16 + u] = ((const ushort*)vg)[(size_t)(row0 + i) * 2048 + hh * 64 + v16 + u];
    }
    __syncthreads();
    if (tid < 32) {
        float run = 0.f;
        for (int j = 0; j < CHK; ++j) { run += glog[j][tid]; glog[j][tid] = run; }
    }
    __syncthreads();
    #pragma unroll
    for (int u = 0; u < 8; ++u) {
        float cl = glog[i][k8 + u];
        float cl63 = glog[CHK - 1][k8 + u];
        clbuf[(size_t)(row0 + i) * 512 + hh * 32 + k8 + u] = cl;
        wk[i][k8 + u] = expf(fmaxf(cl63 - cl, -60.f)) *
            b2f(qk[(size_t)(row0 + i) * 1024 + 512 + hh * 32 + k8 + u]);
    }
    if (tid < 32) Dbuf[(size_t)(bh * 32 + c) * 32 + tid] = expf(glog[CHK - 1][tid]);
    __syncthreads();
    int kk = tid >> 3, v8 = (tid & 7) * 8;
    float acc[8] = {};
    for (int j = 0; j < CHK; ++j) {
        float w = wk[j][kk];
        uint4 raw = *(const uint4*)&vt[j][v8];
        acc8(w, raw, acc);
    }
    float* Pp = Pbuf + (size_t)(bh * 32 + c) * 2048 + kk * 64 + v8;
    #pragma unroll
    for (int u = 0; u < 8; ++u) Pp[u] = acc[u];
}

// ---------------- GLA phase 2: scan ----------------
__global__ __launch_bounds__(256) void gla_scan(
    const float* __restrict__ Pbuf, const float* __restrict__ Dbuf,
    float* __restrict__ Sbuf)
{
    int bh = blockIdx.x >> 3, vg8 = blockIdx.x & 7;
    int kk = threadIdx.x >> 3, vv = vg8 * 8 + (threadIdx.x & 7);
    float S = 0.f;
    for (int c = 0; c < NC; ++c) {
        size_t idx = (size_t)(bh * 32 + c) * 2048 + kk * 64 + vv;
        float P = Pbuf[idx];
        float D = Dbuf[(size_t)(bh * 32 + c) * 32 + kk];
        Sbuf[idx] = S;
        S = D * S + P;
    }
}

// ---------------- GLA phase 3 ----------------
__global__ __launch_bounds__(256) void gla_phase3(
    const bf16* __restrict__ qk, const bf16* __restrict__ vg,
    const float* __restrict__ clbuf, const float* __restrict__ Sbuf,
    const bf16* __restrict__ rmsw, bf16* __restrict__ obuf)
{
    int bh = blockIdx.x, c = blockIdx.y;
    int b = bh >> 4, hh = bh & 15;
    int row0 = b * 2048 + c * CHK;
    __shared__ float qs[CHK][DK], ks[CHK][DK], S0[DK][DV];
    __shared__ float Amat[CHK][CHK];
    __shared__ __align__(16) ushort vt[CHK][DV];
    int tid = threadIdx.x;
    int i = tid >> 2;
    {
        int k8 = (tid & 3) * 8;
        size_t r = (size_t)(row0 + i);
        #pragma unroll
        for (int u = 0; u < 8; ++u) {
            int col = hh * 32 + k8 + u;
            float cl = fmaxf(clbuf[r * 512 + col], -60.f);
            qs[i][k8 + u] = b2f(qk[r * 1024 + col]) * expf(cl) * 0.17677669529663687f;
            ks[i][k8 + u] = b2f(qk[r * 1024 + 512 + col]) * expf(-cl);
        }
        int v16 = (tid & 3) * 16;
        #pragma unroll
        for (int u = 0; u < 16; ++u)
            vt[i][v16 + u] = ((const ushort*)vg)[r * 2048 + hh * 64 + v16 + u];
    }
    {
        int kk = tid >> 3, v8 = (tid & 7) * 8;
        const float* Sp = Sbuf + (size_t)(bh * 32 + c) * 2048 + kk * 64 + v8;
        #pragma unroll
        for (int u = 0; u < 8; ++u) S0[kk][v8 + u] = Sp[u];
    }
    __syncthreads();
    {
        int j0 = (tid & 3) * 16;
        for (int j = j0; j < j0 + 16; ++j) {
            float d = 0.f;
            if (j <= i) {
                const f32x4* qp = (const f32x4*)qs[i];
                const f32x4* kp = (const f32x4*)ks[j];
                #pragma unroll
                for (int q8 = 0; q8 < 8; ++q8) {
                    f32x4 a = qp[q8], bq = kp[q8];
                    d += a.x * bq.x + a.y * bq.y + a.z * bq.z + a.w * bq.w;
                }
            }
            Amat[i][j] = d;
        }
    }
    __syncthreads();
    float o[16] = {};
    int vv = (tid & 3) * 16;
    for (int j = 0; j < CHK; ++j) {
        float a = Amat[i][j];
        uint4 r0 = *(const uint4*)&vt[j][vv];
        uint4 r1 = *(const uint4*)&vt[j][vv + 8];
        acc8(a, r0, o);
        acc8(a, r1, o + 8);
    }
    #pragma unroll
    for (int kk = 0; kk < DK; ++kk) {
        float qv = qs[i][kk];
        const f32x4* Sp = (const f32x4*)&S0[kk][vv];
        #pragma unroll
        for (int q4 = 0; q4 < 4; ++q4) {
            f32x4 sv = Sp[q4];
            o[q4 * 4 + 0] += qv * sv.x; o[q4 * 4 + 1] += qv * sv.y;
            o[q4 * 4 + 2] += qv * sv.z; o[q4 * 4 + 3] += qv * sv.w;
        }
    }
    float ss = 0.f;
    #pragma unroll
    for (int u = 0; u < 16; ++u) ss += o[u] * o[u];
    ss += __shfl_xor(ss, 1);
    ss += __shfl_xor(ss, 2);
    float sc = rsqrtf(fmaxf(ss, 0.f) * (1.f / DV) + 1e-5f);
    size_t r = (size_t)(row0 + i);
    #pragma unroll
    for (int u = 0; u < 16; ++u) {
        float g = b2f(vg[r * 2048 + 1024 + hh * 64 + vv + u]);
        float sw = g / (1.f + expf(-g));
        obuf[r * 1024 + hh * 64 + vv + u] = f2b(clampf(o[u] * sc * b2f(rmsw[vv + u]) * sw, 3e4f));
    }
}

// ---------------- launcher ----------------
extern "C" void kernel_launch(void* const* d_in, const int* in_sizes, int n_in,
                              void* d_out, int out_size, void* d_ws, size_t ws_size,
                              hipStream_t stream) {
    (void)in_sizes; (void)n_in; (void)out_size; (void)ws_size;

    char* ws = (char*)d_ws;
    const size_t MB = 1024 * 1024;
    const size_t KB = 1024;
    // pipeline buffers (as round 2/3)
    bf16*  WqkT = (bf16*)(ws + 0);
    bf16*  WkT  = (bf16*)(ws + 1 * MB);
    bf16*  WvgT = (bf16*)(ws + 2 * MB);
    bf16*  WgT  = (bf16*)(ws + 4 * MB);
    bf16*  WoT  = (bf16*)(ws + 6 * MB);
    bf16*  W1T  = (bf16*)(ws + 8 * MB);
    bf16*  W2T  = (bf16*)(ws + 12 * MB);
    bf16*  hbuf = (bf16*)(ws + 16 * MB);
    bf16*  qkb  = (bf16*)(ws + 24 * MB);
    bf16*  vgb  = (bf16*)(ws + 32 * MB);
    bf16*  gkb  = (bf16*)(ws + 48 * MB);
    float* clbf = (float*)(ws + 52 * MB);
    float* Dbuf = (float*)(ws + 60 * MB);
    float* Pbuf = (float*)(ws + 61 * MB);
    float* Sbuf = (float*)(ws + 69 * MB);
    bf16*  obuf = (bf16*)(ws + 61 * MB);   // aliases Pbuf (dead after scan)
    float* ybuf = (float*)(ws + 32 * MB);  // aliases vgb (dead after phase3)
    bf16*  f1   = (bf16*)(ws + 48 * MB);   // aliases gkb/clbf/Dbuf/obuf-head (all dead)
    // canonical bf16 inputs (77 MB+)
    bf16* cx   = (bf16*)(ws + 77 * MB);
    bf16* cWq  = (bf16*)(ws + 85 * MB);
    bf16* cWk  = (bf16*)(ws + 86 * MB);
    bf16* cWv  = (bf16*)(ws + 87 * MB);
    bf16* cWg  = (bf16*)(ws + 89 * MB);
    bf16* cWo  = (bf16*)(ws + 91 * MB);
    bf16* cW1  = (bf16*)(ws + 93 * MB);
    bf16* cW2  = (bf16*)(ws + 97 * MB);
    bf16* clnw = (bf16*)(ws + 101 * MB);
    bf16* clnb = (bf16*)(ws + 101 * MB + 64 * KB);
    bf16* cgw1 = (bf16*)(ws + 101 * MB + 128 * KB);
    bf16* cgw2 = (bf16*)(ws + 101 * MB + 192 * KB);
    bf16* cgb2 = (bf16*)(ws + 101 * MB + 256 * KB);
    bf16* crms = (bf16*)(ws + 101 * MB + 320 * KB);
    bf16* cb1  = (bf16*)(ws + 101 * MB + 384 * KB);
    bf16* cb2  = (bf16*)(ws + 101 * MB + 448 * KB);
    int*  flag = (int*)(ws + 101 * MB + 512 * KB);

    // 1. detect dtype from x
    hipLaunchKernelGGL(detect_dtype, dim3(1), dim3(256), 0, stream,
                       (const unsigned int*)d_in[0], flag);

    // 2. canonicalize all 16 inputs to bf16
    struct CV { const void* src; bf16* dst; int n; };
    const CV cvs[16] = {
        { d_in[0],  cx,   4194304 }, { d_in[1],  clnw, 1024 },
        { d_in[2],  clnb, 1024 },    { d_in[3],  cWq,  524288 },
        { d_in[4],  cWk,  524288 },  { d_in[5],  cWv,  1048576 },
        { d_in[6],  cgw1, 16384 },   { d_in[7],  cgw2, 8192 },
        { d_in[8],  cgb2, 512 },     { d_in[9],  cWg,  1048576 },
        { d_in[10], crms, 64 },      { d_in[11], cWo,  1048576 },
        { d_in[12], cW1,  2097152 }, { d_in[13], cb1,  2048 },
        { d_in[14], cW2,  2097152 }, { d_in[15], cb2,  1024 },
    };
    for (int i = 0; i < 16; ++i) {
        int blocks = (cvs[i].n + 255) / 256;
        if (blocks > 2048) blocks = 2048;
        hipLaunchKernelGGL(cvt_to_bf16, dim3(blocks), dim3(256), 0, stream,
                           cvs[i].src, cvs[i].dst, cvs[i].n, flag);
    }

    // 3. weight transposes (canonical bf16 sources)
    dim3 tb(32, 8);
    hipLaunchKernelGGL(transpose_bf16, dim3(16, 32), tb, 0, stream, (const ushort*)cWq, (ushort*)WqkT, 1024, 512);
    hipLaunchKernelGGL(transpose_bf16, dim3(16, 32), tb, 0, stream, (const ushort*)cWk, (ushort*)WkT, 1024, 512);
    hipLaunchKernelGGL(transpose_bf16, dim3(32, 32), tb, 0, stream, (const ushort*)cWv, (ushort*)WvgT, 1024, 1024);
    hipLaunchKernelGGL(transpose_bf16, dim3(32, 32), tb, 0, stream, (const ushort*)cWg, (ushort*)WgT, 1024, 1024);
    hipLaunchKernelGGL(transpose_bf16, dim3(32, 32), tb, 0, stream, (const ushort*)cWo, (ushort*)WoT, 1024, 1024);
    hipLaunchKernelGGL(transpose_bf16, dim3(64, 32), tb, 0, stream, (const ushort*)cW1, (ushort*)W1T, 1024, 2048);
    hipLaunchKernelGGL(transpose_bf16, dim3(32, 64), tb, 0, stream, (const ushort*)cW2, (ushort*)W2T, 2048, 1024);

    // 4. pipeline (identical to verified round-2/3 structure)
    hipLaunchKernelGGL((ln_kernel<bf16>), dim3(BT), dim3(256), 0, stream, cx, clnw, clnb, hbuf);

    hipLaunchKernelGGL((gemm_bt<0>), dim3(64, 16), dim3(256), 0, stream,
                       hbuf, WqkT, (const bf16*)nullptr, (const void*)nullptr, (void*)qkb, BT, 1024, 1024, (const int*)nullptr);
    hipLaunchKernelGGL((gemm_bt<0>), dim3(64, 32), dim3(256), 0, stream,
                       hbuf, WvgT, (const bf16*)nullptr, (const void*)nullptr, (void*)vgb, BT, 2048, 1024, (const int*)nullptr);
    hipLaunchKernelGGL(gk_kernel, dim3(BT), dim3(256), 0, stream, hbuf, cgw1, cgw2, cgb2, gkb);

    hipLaunchKernelGGL(gla_phase1, dim3(32, 32), dim3(256), 0, stream, gkb, qkb, vgb, clbf, Dbuf, Pbuf);
    hipLaunchKernelGGL(gla_scan, dim3(256), dim3(256), 0, stream, Pbuf, Dbuf, Sbuf);
    hipLaunchKernelGGL(gla_phase3, dim3(32, 32), dim3(256), 0, stream, qkb, vgb, clbf, Sbuf, crms, obuf);

    hipLaunchKernelGGL((gemm_bt<1>), dim3(64, 16), dim3(256), 0, stream,
                       obuf, WoT, (const bf16*)nullptr, (const void*)cx, (void*)ybuf, BT, 1024, 1024, (const int*)nullptr);
    hipLaunchKernelGGL((ln_kernel<float>), dim3(BT), dim3(256), 0, stream, ybuf, clnw, clnb, hbuf);
    hipLaunchKernelGGL((gemm_bt<2>), dim3(64, 32), dim3(256), 0, stream,
                       hbuf, W1T, cb1, (const void*)nullptr, (void*)f1, BT, 2048, 1024, (const int*)nullptr);
    hipLaunchKernelGGL((gemm_bt<3>), dim3(64, 16), dim3(256), 0, stream,
                       f1, W2T, cb2, (const void*)ybuf, d_out, BT, 1024, 2048, flag);
}

// Round 5
// 459.481 us; speedup vs baseline: 1.0158x; 1.0158x over previous
//
#include <hip/hip_runtime.h>
#include <hip/hip_bf16.h>
#include <math.h>

// GLA block, MI355X. Round 5: m97-style GEMM (128x64 tile, fragment-order LDS,
// global_load_lds w16) + LDS bank-conflict fixes in GLA phase1/phase3 + fused
// weight cvt+transpose. Pipeline semantics identical to round-4 (passed).

using bf16 = __hip_bfloat16;
typedef __attribute__((ext_vector_type(8))) short bf16x8;
typedef __attribute__((ext_vector_type(4))) float f32x4;

#define BT 4096
#define HM 1024
#define DK 32
#define DV 64
#define NC 32
#define CHK 64

#if defined(__has_builtin)
#if __has_builtin(__builtin_amdgcn_global_load_lds)
#define HAVE_GLDS 1
#endif
#endif

#ifdef HAVE_GLDS
#define GLDS16(g, l) __builtin_amdgcn_global_load_lds( \
    (const __attribute__((address_space(1))) unsigned int*)(g), \
    (__attribute__((address_space(3))) unsigned int*)(l), 16, 0, 0)
#else
#define GLDS16(g, l) (*(int4*)(l) = *(const int4*)(g))
#endif

__device__ __forceinline__ float b2f(bf16 v) { return __bfloat162float(v); }
__device__ __forceinline__ bf16 f2b(float v) { return __float2bfloat16(v); }
__device__ __forceinline__ float clampf(float v, float lim) {
    return fminf(fmaxf(v, -lim), lim);
}
__device__ __forceinline__ float lo16(unsigned int u) {
    union { unsigned int i; float f; } c; c.i = u << 16; return c.f;
}
__device__ __forceinline__ float hi16(unsigned int u) {
    union { unsigned int i; float f; } c; c.i = u & 0xffff0000u; return c.f;
}
__device__ __forceinline__ void acc8(float a, uint4 r, float* o) {
    o[0] += a * lo16(r.x); o[1] += a * hi16(r.x);
    o[2] += a * lo16(r.y); o[3] += a * hi16(r.y);
    o[4] += a * lo16(r.z); o[5] += a * hi16(r.z);
    o[6] += a * lo16(r.w); o[7] += a * hi16(r.w);
}

// ---------------- dtype detector ----------------
__global__ __launch_bounds__(256) void detect_dtype(
    const unsigned int* __restrict__ x, int* __restrict__ flag)
{
    int tid = threadIdx.x;
    int cnt = 0;
    for (int i = 0; i < 16; ++i) {
        unsigned int w = x[tid * 16 + i];
        unsigned int e_lo = (w >> 7) & 0xffu;
        unsigned int e_hi = (w >> 23) & 0xffu;
        cnt += (e_lo >= 110 && e_lo <= 135 && e_hi >= 110 && e_hi <= 135) ? 1 : 0;
    }
    __shared__ int red[256];
    red[tid] = cnt;
    __syncthreads();
    for (int s = 128; s > 0; s >>= 1) {
        if (tid < s) red[tid] += red[tid + s];
        __syncthreads();
    }
    if (tid == 0) *flag = (red[0] > 2048) ? 1 : 0;  // 1 = bf16 buffers, 0 = f32
}

// ---------------- canonicalize x -> bf16 ----------------
__global__ __launch_bounds__(256) void cvt_to_bf16(
    const void* __restrict__ src, bf16* __restrict__ dst, int n,
    const int* __restrict__ flag)
{
    bool isb = (*flag != 0);
    int i = blockIdx.x * 256 + threadIdx.x;
    int stride = gridDim.x * 256;
    for (; i < n; i += stride) {
        if (isb) ((ushort*)dst)[i] = ((const ushort*)src)[i];
        else     dst[i] = f2b(((const float*)src)[i]);
    }
}

// ---------------- fused small-tensor cvt (8 segments, one dispatch) ----------
struct SmallCvt { const void* s[8]; bf16* d[8]; int n[8]; };
__global__ __launch_bounds__(256) void cvt_small(SmallCvt sc, const int* __restrict__ flag)
{
    bool isb = (*flag != 0);
    int stride = gridDim.x * 256;
    #pragma unroll
    for (int seg = 0; seg < 8; ++seg) {
        int n = sc.n[seg];
        for (int i = blockIdx.x * 256 + threadIdx.x; i < n; i += stride) {
            if (isb) ((ushort*)sc.d[seg])[i] = ((const ushort*)sc.s[seg])[i];
            else     sc.d[seg][i] = f2b(((const float*)sc.s[seg])[i]);
        }
    }
}

// ---------------- transpose (+cvt): src[R][C] -> dst[C][R] bf16 --------------
__global__ __launch_bounds__(256) void transpose_any(
    const void* __restrict__ src, ushort* __restrict__ dst, int R, int C,
    const int* __restrict__ flag)
{
    bool isb = (*flag != 0);
    __shared__ ushort tile[32][33];
    int c0 = blockIdx.x * 32, r0 = blockIdx.y * 32;
    int x = threadIdx.x, y = threadIdx.y;  // 32 x 8
    #pragma unroll
    for (int dy = 0; dy < 32; dy += 8) {
        size_t idx = (size_t)(r0 + y + dy) * C + c0 + x;
        ushort v;
        if (isb) v = ((const ushort*)src)[idx];
        else { bf16 t = f2b(((const float*)src)[idx]); v = *(ushort*)&t; }
        tile[y + dy][x] = v;
    }
    __syncthreads();
    #pragma unroll
    for (int dy = 0; dy < 32; dy += 8)
        dst[(size_t)(c0 + y + dy) * R + r0 + x] = tile[x][y + dy];
}

// ---------------- LayerNorm: rows of 1024, out bf16 ----------------
template <typename TI>
__global__ __launch_bounds__(256) void ln_kernel(
    const TI* __restrict__ x, const bf16* __restrict__ w, const bf16* __restrict__ b,
    bf16* __restrict__ out)
{
    size_t base = (size_t)blockIdx.x * HM;
    int tid = threadIdx.x;
    float v[4], s = 0.f, s2 = 0.f;
    #pragma unroll
    for (int u = 0; u < 4; ++u) {
        float f;
        if constexpr (sizeof(TI) == 2) f = b2f(((const bf16*)x)[base + tid + u * 256]);
        else                           f = ((const float*)x)[base + tid + u * 256];
        v[u] = f; s += f; s2 += f * f;
    }
    #pragma unroll
    for (int off = 32; off >= 1; off >>= 1) {
        s  += __shfl_down(s, off);
        s2 += __shfl_down(s2, off);
    }
    __shared__ float ra[4], rb[4];
    int wave = tid >> 6;
    if ((tid & 63) == 0) { ra[wave] = s; rb[wave] = s2; }
    __syncthreads();
    s = ra[0] + ra[1] + ra[2] + ra[3];
    s2 = rb[0] + rb[1] + rb[2] + rb[3];
    float mean = s * (1.f / HM);
    float var = fmaxf(s2 * (1.f / HM) - mean * mean, 0.f);
    float rs = rsqrtf(var + 1e-5f);
    #pragma unroll
    for (int u = 0; u < 4; ++u) {
        int col = tid + u * 256;
        out[base + col] = f2b((v[u] - mean) * rs * b2f(w[col]) + b2f(b[col]));
    }
}

// ---------------- gate low-rank MLP ----------------
__global__ __launch_bounds__(256) void gk_kernel(
    const bf16* __restrict__ h, const bf16* __restrict__ w1,
    const bf16* __restrict__ w2, const bf16* __restrict__ b2i,
    bf16* __restrict__ gkout)
{
    size_t row = blockIdx.x;
    const bf16* hr = h + row * HM;
    int tid = threadIdx.x;
    int d = tid & 15, seg = tid >> 4;
    float s = 0.f;
    for (int j = 0; j < 64; ++j) {
        int i = seg * 64 + j;
        s += b2f(hr[i]) * b2f(w1[i * 16 + d]);
    }
    __shared__ float red[256];
    __shared__ float g1[16];
    red[tid] = s;
    __syncthreads();
    if (tid < 16) {
        float t = 0.f;
        #pragma unroll
        for (int sg = 0; sg < 16; ++sg) t += red[sg * 16 + tid];
        g1[tid] = t;
    }
    __syncthreads();
    #pragma unroll
    for (int rep = 0; rep < 2; ++rep) {
        int n = tid + rep * 256;
        float z = b2f(b2i[n]);
        #pragma unroll
        for (int r = 0; r < 16; ++r) z += g1[r] * b2f(w2[r * 512 + n]);
        z = clampf(z, 30.f);
        float ls = (z >= 0.f) ? -log1pf(expf(-z)) : (z - log1pf(expf(z)));
        gkout[row * 512 + n] = f2b(ls * 0.0625f);
    }
}

// ---------------- MFMA GEMM 128x64: C[M,N] = A[M,K] @ Wt[N,K]^T --------------
// LDS in fragment order: elem(row,col) -> idx = (row>>4)*512 + (col>>3)*128
//   + (row&15)*8 + (col&7). Frag reads become lane-sequential 16B.
// Staging: wave w lane l issue i covers LDS idx (i*2048 + w*512 + l*8) ->
//   global row (i*4+w)*16 + (l&15), col (l>>4)*8.
// MODE 0: ->bf16; 1: f32 = resid_bf16+acc; 2: bf16 = gelu(acc+bias);
// MODE 3: resid_f32+acc+bias -> f32 or bf16 per oflag
template <int MODE>
__global__ __launch_bounds__(256) void gemm_bt(
    const bf16* __restrict__ A, const bf16* __restrict__ Wt,
    const bf16* __restrict__ bias, const void* __restrict__ resid,
    void* __restrict__ out, int M, int N, int K, const int* __restrict__ oflag)
{
    __shared__ __align__(16) ushort As[128 * 32];
    __shared__ __align__(16) ushort Bs[64 * 32];
    int tid = threadIdx.x;
    int w = tid >> 6, l = tid & 63;
    int bm = blockIdx.x * 128, bn = blockIdx.y * 64;
    int row16 = l & 15, quad = l >> 4;
    bool out_bf16 = false;
    if constexpr (MODE == 3) out_bf16 = (*oflag != 0);

    const ushort* Au = (const ushort*)A;
    const ushort* Wu = (const ushort*)Wt;
    int sr = w * 16 + row16;
    int scol = quad * 8;
    const ushort* gA0 = Au + (size_t)(bm + sr) * K + scol;
    const ushort* gA1 = Au + (size_t)(bm + sr + 64) * K + scol;
    const ushort* gB0 = Wu + (size_t)(bn + sr) * K + scol;
    ushort* lA0 = &As[w * 512 + l * 8];
    ushort* lA1 = &As[2048 + w * 512 + l * 8];
    ushort* lB0 = &Bs[w * 512 + l * 8];

    int am = (w >> 1) * 4;       // r16 base for this wave's M rows
    int an = (w & 1) * 2;        // r16 base for this wave's N rows
    int fo = quad * 128 + row16 * 8;

    f32x4 acc[4][2] = {};
    for (int k0 = 0; k0 < K; k0 += 32) {
        GLDS16(gA0 + k0, lA0);
        GLDS16(gA1 + k0, lA1);
        GLDS16(gB0 + k0, lB0);
        __syncthreads();
        bf16x8 af[4], bff[2];
        #pragma unroll
        for (int mi = 0; mi < 4; ++mi) af[mi] = *(const bf16x8*)&As[(am + mi) * 512 + fo];
        #pragma unroll
        for (int ni = 0; ni < 2; ++ni) bff[ni] = *(const bf16x8*)&Bs[(an + ni) * 512 + fo];
        #pragma unroll
        for (int mi = 0; mi < 4; ++mi)
            #pragma unroll
            for (int ni = 0; ni < 2; ++ni)
                acc[mi][ni] = __builtin_amdgcn_mfma_f32_16x16x32_bf16(af[mi], bff[ni], acc[mi][ni], 0, 0, 0);
        __syncthreads();
    }
    #pragma unroll
    for (int mi = 0; mi < 4; ++mi) {
        #pragma unroll
        for (int ni = 0; ni < 2; ++ni) {
            int col = bn + (w & 1) * 32 + ni * 16 + row16;
            #pragma unroll
            for (int r = 0; r < 4; ++r) {
                int row = bm + (w >> 1) * 64 + mi * 16 + quad * 4 + r;
                size_t idx = (size_t)row * N + col;
                float v = acc[mi][ni][r];
                if constexpr (MODE == 0) {
                    ((bf16*)out)[idx] = f2b(clampf(v, 1e4f));
                } else if constexpr (MODE == 1) {
                    ((float*)out)[idx] = clampf(b2f(((const bf16*)resid)[idx]) + v, 1e5f);
                } else if constexpr (MODE == 2) {
                    float t = clampf(v + b2f(bias[col]), 50.f);
                    ((bf16*)out)[idx] = f2b(0.5f * t * (1.f + erff(t * 0.70710678f)));
                } else {
                    float t = clampf(v + b2f(bias[col]) + ((const float*)resid)[idx], 2e5f);
                    if (out_bf16) ((bf16*)out)[idx] = f2b(t);
                    else          ((float*)out)[idx] = t;
                }
            }
        }
    }
}

// ---------------- GLA phase 1 (conflict-fixed) ----------------
__global__ __launch_bounds__(256) void gla_phase1(
    const bf16* __restrict__ gkb, const bf16* __restrict__ qk,
    const bf16* __restrict__ vg,
    float* __restrict__ clbuf, float* __restrict__ Dbuf, float* __restrict__ Pbuf)
{
    int bh = blockIdx.x, c = blockIdx.y;
    int b = bh >> 4, hh = bh & 15;
    int row0 = b * 2048 + c * CHK;
    __shared__ float glog[CHK][DK + 1];
    __shared__ float wk[CHK][DK + 1];
    __shared__ __align__(16) ushort vt[CHK][DV];
    int tid = threadIdx.x;
    int k = tid & 31, i8 = (tid >> 5) * 8;
    #pragma unroll
    for (int u = 0; u < 8; ++u) {
        int i = i8 + u;
        float g = b2f(gkb[(size_t)(row0 + i) * 512 + hh * 32 + k]);
        glog[i][k] = fminf(fmaxf(g, -2.f), 0.f);
    }
    {
        int cc = tid & 7, ii = tid >> 3;
        #pragma unroll
        for (int h = 0; h < 2; ++h) {
            int i = ii + h * 32;
            uint4 val = *(const uint4*)((const ushort*)vg + (size_t)(row0 + i) * 2048 + hh * 64 + cc * 8);
            *(uint4*)&vt[i][cc * 8] = val;
        }
    }
    __syncthreads();
    if (tid < 32) {
        float run = 0.f;
        for (int j = 0; j < CHK; ++j) { run += glog[j][tid]; glog[j][tid] = run; }
    }
    __syncthreads();
    #pragma unroll
    for (int u = 0; u < 8; ++u) {
        int i = i8 + u;
        float cl = glog[i][k];
        float cl63 = glog[CHK - 1][k];
        clbuf[(size_t)(row0 + i) * 512 + hh * 32 + k] = cl;
        wk[i][k] = expf(fmaxf(cl63 - cl, -60.f)) *
            b2f(qk[(size_t)(row0 + i) * 1024 + 512 + hh * 32 + k]);
    }
    if (tid < 32) Dbuf[(size_t)(bh * 32 + c) * 32 + tid] = expf(glog[CHK - 1][tid]);
    __syncthreads();
    int kk = tid >> 3, v8 = (tid & 7) * 8;
    float acc[8] = {};
    for (int j = 0; j < CHK; ++j) {
        float w = wk[j][kk];
        uint4 raw = *(const uint4*)&vt[j][v8];
        acc8(w, raw, acc);
    }
    float* Pp = Pbuf + (size_t)(bh * 32 + c) * 2048 + kk * 64 + v8;
    #pragma unroll
    for (int u = 0; u < 8; ++u) Pp[u] = acc[u];
}

// ---------------- GLA phase 2: scan ----------------
__global__ __launch_bounds__(256) void gla_scan(
    const float* __restrict__ Pbuf, const float* __restrict__ Dbuf,
    float* __restrict__ Sbuf)
{
    int bh = blockIdx.x >> 3, vg8 = blockIdx.x & 7;
    int kk = threadIdx.x >> 3, vv = vg8 * 8 + (threadIdx.x & 7);
    float S = 0.f;
    for (int c = 0; c < NC; ++c) {
        size_t idx = (size_t)(bh * 32 + c) * 2048 + kk * 64 + vv;
        float P = Pbuf[idx];
        float D = Dbuf[(size_t)(bh * 32 + c) * 32 + kk];
        Sbuf[idx] = S;
        S = D * S + P;
    }
}

// ---------------- GLA phase 3 (conflict-fixed) ----------------
__global__ __launch_bounds__(256) void gla_phase3(
    const bf16* __restrict__ qk, const bf16* __restrict__ vg,
    const float* __restrict__ clbuf, const float* __restrict__ Sbuf,
    const bf16* __restrict__ rmsw, bf16* __restrict__ obuf)
{
    int bh = blockIdx.x, c = blockIdx.y;
    int b = bh >> 4, hh = bh & 15;
    int row0 = b * 2048 + c * CHK;
    __shared__ float qs[CHK][36], ks[CHK][36];   // padded, 16B-aligned rows
    __shared__ float S0[DK][68];
    __shared__ float Amat[CHK][CHK + 1];
    __shared__ __align__(16) ushort vt[CHK][DV];
    int tid = threadIdx.x;
    {
        int k = tid & 31, i8 = (tid >> 5) * 8;
        #pragma unroll
        for (int u = 0; u < 8; ++u) {
            int i = i8 + u;
            size_t r = (size_t)(row0 + i);
            int col = hh * 32 + k;
            float cl = fmaxf(clbuf[r * 512 + col], -60.f);
            qs[i][k] = b2f(qk[r * 1024 + col]) * expf(cl) * 0.17677669529663687f;
            ks[i][k] = b2f(qk[r * 1024 + 512 + col]) * expf(-cl);
        }
    }
    {
        int cc = tid & 7, ii = tid >> 3;
        #pragma unroll
        for (int h = 0; h < 2; ++h) {
            int i = ii + h * 32;
            uint4 val = *(const uint4*)((const ushort*)vg + (size_t)(row0 + i) * 2048 + hh * 64 + cc * 8);
            *(uint4*)&vt[i][cc * 8] = val;
        }
    }
    {
        int kk = tid >> 3, v8 = (tid & 7) * 8;
        const float* Sp = Sbuf + (size_t)(bh * 32 + c) * 2048 + kk * 64 + v8;
        *(f32x4*)&S0[kk][v8]     = *(const f32x4*)Sp;
        *(f32x4*)&S0[kk][v8 + 4] = *(const f32x4*)(Sp + 4);
    }
    __syncthreads();
    int i = tid >> 2, jb = tid & 3;
    for (int jj = 0; jj < 16; ++jj) {
        int j = jb + jj * 4;
        float d = 0.f;
        if (j <= i) {
            const f32x4* qp = (const f32x4*)qs[i];
            const f32x4* kp = (const f32x4*)ks[j];
            #pragma unroll
            for (int q8 = 0; q8 < 8; ++q8) {
                f32x4 a = qp[q8], bq = kp[q8];
                d += a.x * bq.x + a.y * bq.y + a.z * bq.z + a.w * bq.w;
            }
        }
        Amat[i][j] = d;
    }
    __syncthreads();
    float o[16] = {};
    int vv = jb * 16;
    for (int j = 0; j < CHK; ++j) {
        float a = Amat[i][j];
        uint4 r0 = *(const uint4*)&vt[j][vv];
        uint4 r1 = *(const uint4*)&vt[j][vv + 8];
        acc8(a, r0, o);
        acc8(a, r1, o + 8);
    }
    #pragma unroll
    for (int kk = 0; kk < DK; ++kk) {
        float qv = qs[i][kk];
        const f32x4* Sp = (const f32x4*)&S0[kk][vv];
        #pragma unroll
        for (int q4 = 0; q4 < 4; ++q4) {
            f32x4 sv = Sp[q4];
            o[q4 * 4 + 0] += qv * sv.x; o[q4 * 4 + 1] += qv * sv.y;
            o[q4 * 4 + 2] += qv * sv.z; o[q4 * 4 + 3] += qv * sv.w;
        }
    }
    float ss = 0.f;
    #pragma unroll
    for (int u = 0; u < 16; ++u) ss += o[u] * o[u];
    ss += __shfl_xor(ss, 1);
    ss += __shfl_xor(ss, 2);
    float sc = rsqrtf(fmaxf(ss, 0.f) * (1.f / DV) + 1e-5f);
    size_t r = (size_t)(row0 + i);
    #pragma unroll
    for (int u = 0; u < 16; ++u) {
        float g = b2f(vg[r * 2048 + 1024 + hh * 64 + vv + u]);
        float sw = g / (1.f + expf(-g));
        obuf[r * 1024 + hh * 64 + vv + u] = f2b(clampf(o[u] * sc * b2f(rmsw[vv + u]) * sw, 3e4f));
    }
}

// ---------------- launcher ----------------
extern "C" void kernel_launch(void* const* d_in, const int* in_sizes, int n_in,
                              void* d_out, int out_size, void* d_ws, size_t ws_size,
                              hipStream_t stream) {
    (void)in_sizes; (void)n_in; (void)out_size; (void)ws_size;

    char* ws = (char*)d_ws;
    const size_t MB = 1024 * 1024;
    const size_t KB = 1024;
    bf16*  WqkT = (bf16*)(ws + 0);
    bf16*  WkT  = (bf16*)(ws + 1 * MB);
    bf16*  WvgT = (bf16*)(ws + 2 * MB);
    bf16*  WgT  = (bf16*)(ws + 4 * MB);
    bf16*  WoT  = (bf16*)(ws + 6 * MB);
    bf16*  W1T  = (bf16*)(ws + 8 * MB);
    bf16*  W2T  = (bf16*)(ws + 12 * MB);
    bf16*  hbuf = (bf16*)(ws + 16 * MB);
    bf16*  qkb  = (bf16*)(ws + 24 * MB);
    bf16*  vgb  = (bf16*)(ws + 32 * MB);
    bf16*  gkb  = (bf16*)(ws + 48 * MB);
    float* clbf = (float*)(ws + 52 * MB);
    float* Dbuf = (float*)(ws + 60 * MB);
    float* Pbuf = (float*)(ws + 61 * MB);
    float* Sbuf = (float*)(ws + 69 * MB);
    bf16*  obuf = (bf16*)(ws + 61 * MB);   // aliases Pbuf (dead after scan)
    float* ybuf = (float*)(ws + 32 * MB);  // aliases vgb (dead after phase3)
    bf16*  f1   = (bf16*)(ws + 48 * MB);   // aliases gkb/clbf/Dbuf/obuf-head (dead)
    bf16*  cx   = (bf16*)(ws + 77 * MB);
    bf16*  clnw = (bf16*)(ws + 85 * MB);
    bf16*  clnb = (bf16*)(ws + 85 * MB + 64 * KB);
    bf16*  cgw1 = (bf16*)(ws + 85 * MB + 128 * KB);
    bf16*  cgw2 = (bf16*)(ws + 85 * MB + 192 * KB);
    bf16*  cgb2 = (bf16*)(ws + 85 * MB + 256 * KB);
    bf16*  crms = (bf16*)(ws + 85 * MB + 320 * KB);
    bf16*  cb1  = (bf16*)(ws + 85 * MB + 384 * KB);
    bf16*  cb2  = (bf16*)(ws + 85 * MB + 448 * KB);
    int*   flag = (int*)(ws + 85 * MB + 512 * KB);

    // 1. detect dtype
    hipLaunchKernelGGL(detect_dtype, dim3(1), dim3(256), 0, stream,
                       (const unsigned int*)d_in[0], flag);

    // 2. canonicalize x + small tensors
    hipLaunchKernelGGL(cvt_to_bf16, dim3(2048), dim3(256), 0, stream,
                       d_in[0], cx, 4194304, flag);
    SmallCvt sc;
    sc.s[0] = d_in[1];  sc.d[0] = clnw; sc.n[0] = 1024;
    sc.s[1] = d_in[2];  sc.d[1] = clnb; sc.n[1] = 1024;
    sc.s[2] = d_in[6];  sc.d[2] = cgw1; sc.n[2] = 16384;
    sc.s[3] = d_in[7];  sc.d[3] = cgw2; sc.n[3] = 8192;
    sc.s[4] = d_in[8];  sc.d[4] = cgb2; sc.n[4] = 512;
    sc.s[5] = d_in[10]; sc.d[5] = crms; sc.n[5] = 64;
    sc.s[6] = d_in[13]; sc.d[6] = cb1;  sc.n[6] = 2048;
    sc.s[7] = d_in[15]; sc.d[7] = cb2;  sc.n[7] = 1024;
    hipLaunchKernelGGL(cvt_small, dim3(64), dim3(256), 0, stream, sc, flag);

    // 3. fused cvt+transpose of the 7 big weights
    dim3 tb(32, 8);
    hipLaunchKernelGGL(transpose_any, dim3(16, 32), tb, 0, stream, d_in[3],  (ushort*)WqkT, 1024, 512, flag);
    hipLaunchKernelGGL(transpose_any, dim3(16, 32), tb, 0, stream, d_in[4],  (ushort*)WkT,  1024, 512, flag);
    hipLaunchKernelGGL(transpose_any, dim3(32, 32), tb, 0, stream, d_in[5],  (ushort*)WvgT, 1024, 1024, flag);
    hipLaunchKernelGGL(transpose_any, dim3(32, 32), tb, 0, stream, d_in[9],  (ushort*)WgT,  1024, 1024, flag);
    hipLaunchKernelGGL(transpose_any, dim3(32, 32), tb, 0, stream, d_in[11], (ushort*)WoT,  1024, 1024, flag);
    hipLaunchKernelGGL(transpose_any, dim3(64, 32), tb, 0, stream, d_in[12], (ushort*)W1T,  1024, 2048, flag);
    hipLaunchKernelGGL(transpose_any, dim3(32, 64), tb, 0, stream, d_in[14], (ushort*)W2T,  2048, 1024, flag);

    // 4. pipeline
    hipLaunchKernelGGL((ln_kernel<bf16>), dim3(BT), dim3(256), 0, stream, cx, clnw, clnb, hbuf);

    hipLaunchKernelGGL((gemm_bt<0>), dim3(32, 16), dim3(256), 0, stream,
                       hbuf, WqkT, (const bf16*)nullptr, (const void*)nullptr, (void*)qkb, BT, 1024, 1024, (const int*)nullptr);
    hipLaunchKernelGGL((gemm_bt<0>), dim3(32, 32), dim3(256), 0, stream,
                       hbuf, WvgT, (const bf16*)nullptr, (const void*)nullptr, (void*)vgb, BT, 2048, 1024, (const int*)nullptr);
    hipLaunchKernelGGL(gk_kernel, dim3(BT), dim3(256), 0, stream, hbuf, cgw1, cgw2, cgb2, gkb);

    hipLaunchKernelGGL(gla_phase1, dim3(32, 32), dim3(256), 0, stream, gkb, qkb, vgb, clbf, Dbuf, Pbuf);
    hipLaunchKernelGGL(gla_scan, dim3(256), dim3(256), 0, stream, Pbuf, Dbuf, Sbuf);
    hipLaunchKernelGGL(gla_phase3, dim3(32, 32), dim3(256), 0, stream, qkb, vgb, clbf, Sbuf, crms, obuf);

    hipLaunchKernelGGL((gemm_bt<1>), dim3(32, 16), dim3(256), 0, stream,
                       obuf, WoT, (const bf16*)nullptr, (const void*)cx, (void*)ybuf, BT, 1024, 1024, (const int*)nullptr);
    hipLaunchKernelGGL((ln_kernel<float>), dim3(BT), dim3(256), 0, stream, ybuf, clnw, clnb, hbuf);
    hipLaunchKernelGGL((gemm_bt<2>), dim3(32, 32), dim3(256), 0, stream,
                       hbuf, W1T, cb1, (const void*)nullptr, (void*)f1, BT, 2048, 1024, (const int*)nullptr);
    hipLaunchKernelGGL((gemm_bt<3>), dim3(32, 16), dim3(256), 0, stream,
                       f1, W2T, cb2, (const void*)ybuf, d_out, BT, 1024, 2048, flag);
}

// Round 6
// 456.061 us; speedup vs baseline: 1.0234x; 1.0075x over previous
//
#include <hip/hip_runtime.h>
#include <hip/hip_bf16.h>
#include <math.h>

// GLA block, MI355X. Round 6: BK=64 GEMM K-loop (16 MFMA/wave per barrier,
// half the barrier drains) + fused qkv+vg GEMM (N=3072, 1536 blocks).
// Pipeline semantics identical to round-4/5 (passed, absmax 0.031).

using bf16 = __hip_bfloat16;
typedef __attribute__((ext_vector_type(8))) short bf16x8;
typedef __attribute__((ext_vector_type(4))) float f32x4;

#define BT 4096
#define HM 1024
#define DK 32
#define DV 64
#define NC 32
#define CHK 64

#if defined(__has_builtin)
#if __has_builtin(__builtin_amdgcn_global_load_lds)
#define HAVE_GLDS 1
#endif
#endif

#ifdef HAVE_GLDS
#define GLDS16(g, l) __builtin_amdgcn_global_load_lds( \
    (const __attribute__((address_space(1))) unsigned int*)(g), \
    (__attribute__((address_space(3))) unsigned int*)(l), 16, 0, 0)
#else
#define GLDS16(g, l) (*(int4*)(l) = *(const int4*)(g))
#endif

__device__ __forceinline__ float b2f(bf16 v) { return __bfloat162float(v); }
__device__ __forceinline__ bf16 f2b(float v) { return __float2bfloat16(v); }
__device__ __forceinline__ float clampf(float v, float lim) {
    return fminf(fmaxf(v, -lim), lim);
}
__device__ __forceinline__ float lo16(unsigned int u) {
    union { unsigned int i; float f; } c; c.i = u << 16; return c.f;
}
__device__ __forceinline__ float hi16(unsigned int u) {
    union { unsigned int i; float f; } c; c.i = u & 0xffff0000u; return c.f;
}
__device__ __forceinline__ void acc8(float a, uint4 r, float* o) {
    o[0] += a * lo16(r.x); o[1] += a * hi16(r.x);
    o[2] += a * lo16(r.y); o[3] += a * hi16(r.y);
    o[4] += a * lo16(r.z); o[5] += a * hi16(r.z);
    o[6] += a * lo16(r.w); o[7] += a * hi16(r.w);
}

// ---------------- dtype detector ----------------
__global__ __launch_bounds__(256) void detect_dtype(
    const unsigned int* __restrict__ x, int* __restrict__ flag)
{
    int tid = threadIdx.x;
    int cnt = 0;
    for (int i = 0; i < 16; ++i) {
        unsigned int w = x[tid * 16 + i];
        unsigned int e_lo = (w >> 7) & 0xffu;
        unsigned int e_hi = (w >> 23) & 0xffu;
        cnt += (e_lo >= 110 && e_lo <= 135 && e_hi >= 110 && e_hi <= 135) ? 1 : 0;
    }
    __shared__ int red[256];
    red[tid] = cnt;
    __syncthreads();
    for (int s = 128; s > 0; s >>= 1) {
        if (tid < s) red[tid] += red[tid + s];
        __syncthreads();
    }
    if (tid == 0) *flag = (red[0] > 2048) ? 1 : 0;  // 1 = bf16 buffers, 0 = f32
}

// ---------------- canonicalize x -> bf16 ----------------
__global__ __launch_bounds__(256) void cvt_to_bf16(
    const void* __restrict__ src, bf16* __restrict__ dst, int n,
    const int* __restrict__ flag)
{
    bool isb = (*flag != 0);
    int i = blockIdx.x * 256 + threadIdx.x;
    int stride = gridDim.x * 256;
    for (; i < n; i += stride) {
        if (isb) ((ushort*)dst)[i] = ((const ushort*)src)[i];
        else     dst[i] = f2b(((const float*)src)[i]);
    }
}

// ---------------- fused small-tensor cvt ----------
struct SmallCvt { const void* s[8]; bf16* d[8]; int n[8]; };
__global__ __launch_bounds__(256) void cvt_small(SmallCvt sc, const int* __restrict__ flag)
{
    bool isb = (*flag != 0);
    int stride = gridDim.x * 256;
    #pragma unroll
    for (int seg = 0; seg < 8; ++seg) {
        int n = sc.n[seg];
        for (int i = blockIdx.x * 256 + threadIdx.x; i < n; i += stride) {
            if (isb) ((ushort*)sc.d[seg])[i] = ((const ushort*)sc.s[seg])[i];
            else     sc.d[seg][i] = f2b(((const float*)sc.s[seg])[i]);
        }
    }
}

// ---------------- transpose (+cvt): src[R][C] -> dst[C][R] bf16 --------------
__global__ __launch_bounds__(256) void transpose_any(
    const void* __restrict__ src, ushort* __restrict__ dst, int R, int C,
    const int* __restrict__ flag)
{
    bool isb = (*flag != 0);
    __shared__ ushort tile[32][33];
    int c0 = blockIdx.x * 32, r0 = blockIdx.y * 32;
    int x = threadIdx.x, y = threadIdx.y;  // 32 x 8
    #pragma unroll
    for (int dy = 0; dy < 32; dy += 8) {
        size_t idx = (size_t)(r0 + y + dy) * C + c0 + x;
        ushort v;
        if (isb) v = ((const ushort*)src)[idx];
        else { bf16 t = f2b(((const float*)src)[idx]); v = *(ushort*)&t; }
        tile[y + dy][x] = v;
    }
    __syncthreads();
    #pragma unroll
    for (int dy = 0; dy < 32; dy += 8)
        dst[(size_t)(c0 + y + dy) * R + r0 + x] = tile[x][y + dy];
}

// ---------------- LayerNorm ----------------
template <typename TI>
__global__ __launch_bounds__(256) void ln_kernel(
    const TI* __restrict__ x, const bf16* __restrict__ w, const bf16* __restrict__ b,
    bf16* __restrict__ out)
{
    size_t base = (size_t)blockIdx.x * HM;
    int tid = threadIdx.x;
    float v[4], s = 0.f, s2 = 0.f;
    #pragma unroll
    for (int u = 0; u < 4; ++u) {
        float f;
        if constexpr (sizeof(TI) == 2) f = b2f(((const bf16*)x)[base + tid + u * 256]);
        else                           f = ((const float*)x)[base + tid + u * 256];
        v[u] = f; s += f; s2 += f * f;
    }
    #pragma unroll
    for (int off = 32; off >= 1; off >>= 1) {
        s  += __shfl_down(s, off);
        s2 += __shfl_down(s2, off);
    }
    __shared__ float ra[4], rb[4];
    int wave = tid >> 6;
    if ((tid & 63) == 0) { ra[wave] = s; rb[wave] = s2; }
    __syncthreads();
    s = ra[0] + ra[1] + ra[2] + ra[3];
    s2 = rb[0] + rb[1] + rb[2] + rb[3];
    float mean = s * (1.f / HM);
    float var = fmaxf(s2 * (1.f / HM) - mean * mean, 0.f);
    float rs = rsqrtf(var + 1e-5f);
    #pragma unroll
    for (int u = 0; u < 4; ++u) {
        int col = tid + u * 256;
        out[base + col] = f2b((v[u] - mean) * rs * b2f(w[col]) + b2f(b[col]));
    }
}

// ---------------- gate low-rank MLP ----------------
__global__ __launch_bounds__(256) void gk_kernel(
    const bf16* __restrict__ h, const bf16* __restrict__ w1,
    const bf16* __restrict__ w2, const bf16* __restrict__ b2i,
    bf16* __restrict__ gkout)
{
    size_t row = blockIdx.x;
    const bf16* hr = h + row * HM;
    int tid = threadIdx.x;
    int d = tid & 15, seg = tid >> 4;
    float s = 0.f;
    for (int j = 0; j < 64; ++j) {
        int i = seg * 64 + j;
        s += b2f(hr[i]) * b2f(w1[i * 16 + d]);
    }
    __shared__ float red[256];
    __shared__ float g1[16];
    red[tid] = s;
    __syncthreads();
    if (tid < 16) {
        float t = 0.f;
        #pragma unroll
        for (int sg = 0; sg < 16; ++sg) t += red[sg * 16 + tid];
        g1[tid] = t;
    }
    __syncthreads();
    #pragma unroll
    for (int rep = 0; rep < 2; ++rep) {
        int n = tid + rep * 256;
        float z = b2f(b2i[n]);
        #pragma unroll
        for (int r = 0; r < 16; ++r) z += g1[r] * b2f(w2[r * 512 + n]);
        z = clampf(z, 30.f);
        float ls = (z >= 0.f) ? -log1pf(expf(-z)) : (z - log1pf(expf(z)));
        gkout[row * 512 + n] = f2b(ls * 0.0625f);
    }
}

// ---------------- MFMA GEMM 128x64, BK=64: C = A[M,K] @ Wt[N,K]^T -----------
// Fragment-order LDS: elem(row,col) -> (row>>4)*1024 + (col>>3)*128
//   + (row&15)*8 + (col&7).   As 128x64 (16KB), Bs 64x64 (8KB).
// Staging j = i*4+w: LDS idx j*512 + l*8  <->  row (j>>1)*16+(l&15),
//   col (j&1)*32 + (l>>4)*8.  (identity verified against fragment formula)
// MODE 0: ->bf16; 1: f32 = resid_bf16+acc; 2: bf16 = gelu(acc+bias);
// MODE 3: resid_f32+acc+bias -> f32 or bf16 per oflag
template <int MODE>
__global__ __launch_bounds__(256) void gemm_bt(
    const bf16* __restrict__ A, const bf16* __restrict__ Wt,
    const bf16* __restrict__ bias, const void* __restrict__ resid,
    void* __restrict__ out, int M, int N, int K, const int* __restrict__ oflag)
{
    __shared__ __align__(16) ushort As[128 * 64];
    __shared__ __align__(16) ushort Bs[64 * 64];
    int tid = threadIdx.x;
    int w = tid >> 6, l = tid & 63;
    int bm = blockIdx.x * 128, bn = blockIdx.y * 64;
    int row16 = l & 15, quad = l >> 4;
    bool out_bf16 = false;
    if constexpr (MODE == 3) out_bf16 = (*oflag != 0);

    const ushort* Au = (const ushort*)A;
    const ushort* Wu = (const ushort*)Wt;

    f32x4 acc[4][2] = {};
    for (int k0 = 0; k0 < K; k0 += 64) {
        #pragma unroll
        for (int i = 0; i < 4; ++i) {
            int j = i * 4 + w;
            const ushort* g = Au + (size_t)(bm + (j >> 1) * 16 + row16) * K
                              + k0 + (j & 1) * 32 + quad * 8;
            GLDS16(g, &As[j * 512 + l * 8]);
        }
        #pragma unroll
        for (int i = 0; i < 2; ++i) {
            int j = i * 4 + w;
            const ushort* g = Wu + (size_t)(bn + (j >> 1) * 16 + row16) * K
                              + k0 + (j & 1) * 32 + quad * 8;
            GLDS16(g, &Bs[j * 512 + l * 8]);
        }
        __syncthreads();
        #pragma unroll
        for (int s = 0; s < 2; ++s) {
            int fo = (s * 4 + quad) * 128 + row16 * 8;
            bf16x8 af[4], bw[2];
            #pragma unroll
            for (int mi = 0; mi < 4; ++mi)
                af[mi] = *(const bf16x8*)&As[((w >> 1) * 4 + mi) * 1024 + fo];
            #pragma unroll
            for (int ni = 0; ni < 2; ++ni)
                bw[ni] = *(const bf16x8*)&Bs[((w & 1) * 2 + ni) * 1024 + fo];
            #pragma unroll
            for (int mi = 0; mi < 4; ++mi)
                #pragma unroll
                for (int ni = 0; ni < 2; ++ni)
                    acc[mi][ni] = __builtin_amdgcn_mfma_f32_16x16x32_bf16(af[mi], bw[ni], acc[mi][ni], 0, 0, 0);
        }
        __syncthreads();
    }
    #pragma unroll
    for (int mi = 0; mi < 4; ++mi) {
        #pragma unroll
        for (int ni = 0; ni < 2; ++ni) {
            int col = bn + (w & 1) * 32 + ni * 16 + row16;
            #pragma unroll
            for (int r = 0; r < 4; ++r) {
                int row = bm + (w >> 1) * 64 + mi * 16 + quad * 4 + r;
                size_t idx = (size_t)row * N + col;
                float v = acc[mi][ni][r];
                if constexpr (MODE == 0) {
                    ((bf16*)out)[idx] = f2b(clampf(v, 1e4f));
                } else if constexpr (MODE == 1) {
                    ((float*)out)[idx] = clampf(b2f(((const bf16*)resid)[idx]) + v, 1e5f);
                } else if constexpr (MODE == 2) {
                    float t = clampf(v + b2f(bias[col]), 50.f);
                    ((bf16*)out)[idx] = f2b(0.5f * t * (1.f + erff(t * 0.70710678f)));
                } else {
                    float t = clampf(v + b2f(bias[col]) + ((const float*)resid)[idx], 2e5f);
                    if (out_bf16) ((bf16*)out)[idx] = f2b(t);
                    else          ((float*)out)[idx] = t;
                }
            }
        }
    }
}

// ---------------- GLA phase 1 (qvg stride 3072) ----------------
__global__ __launch_bounds__(256) void gla_phase1(
    const bf16* __restrict__ gkb,   // [4096][512]
    const bf16* __restrict__ qvg,   // [4096][3072]: q 0-511, k 512-1023, v 1024-2047, g 2048-3071
    float* __restrict__ clbuf, float* __restrict__ Dbuf, float* __restrict__ Pbuf)
{
    int bh = blockIdx.x, c = blockIdx.y;
    int b = bh >> 4, hh = bh & 15;
    int row0 = b * 2048 + c * CHK;
    __shared__ float glog[CHK][DK + 1];
    __shared__ float wk[CHK][DK + 1];
    __shared__ __align__(16) ushort vt[CHK][DV];
    int tid = threadIdx.x;
    int k = tid & 31, i8 = (tid >> 5) * 8;
    #pragma unroll
    for (int u = 0; u < 8; ++u) {
        int i = i8 + u;
        float g = b2f(gkb[(size_t)(row0 + i) * 512 + hh * 32 + k]);
        glog[i][k] = fminf(fmaxf(g, -2.f), 0.f);
    }
    {
        int cc = tid & 7, ii = tid >> 3;
        #pragma unroll
        for (int h = 0; h < 2; ++h) {
            int i = ii + h * 32;
            uint4 val = *(const uint4*)((const ushort*)qvg + (size_t)(row0 + i) * 3072 + 1024 + hh * 64 + cc * 8);
            *(uint4*)&vt[i][cc * 8] = val;
        }
    }
    __syncthreads();
    if (tid < 32) {
        float run = 0.f;
        for (int j = 0; j < CHK; ++j) { run += glog[j][tid]; glog[j][tid] = run; }
    }
    __syncthreads();
    #pragma unroll
    for (int u = 0; u < 8; ++u) {
        int i = i8 + u;
        float cl = glog[i][k];
        float cl63 = glog[CHK - 1][k];
        clbuf[(size_t)(row0 + i) * 512 + hh * 32 + k] = cl;
        wk[i][k] = expf(fmaxf(cl63 - cl, -60.f)) *
            b2f(qvg[(size_t)(row0 + i) * 3072 + 512 + hh * 32 + k]);
    }
    if (tid < 32) Dbuf[(size_t)(bh * 32 + c) * 32 + tid] = expf(glog[CHK - 1][tid]);
    __syncthreads();
    int kk = tid >> 3, v8 = (tid & 7) * 8;
    float acc[8] = {};
    for (int j = 0; j < CHK; ++j) {
        float w = wk[j][kk];
        uint4 raw = *(const uint4*)&vt[j][v8];
        acc8(w, raw, acc);
    }
    float* Pp = Pbuf + (size_t)(bh * 32 + c) * 2048 + kk * 64 + v8;
    #pragma unroll
    for (int u = 0; u < 8; ++u) Pp[u] = acc[u];
}

// ---------------- GLA phase 2: scan ----------------
__global__ __launch_bounds__(256) void gla_scan(
    const float* __restrict__ Pbuf, const float* __restrict__ Dbuf,
    float* __restrict__ Sbuf)
{
    int bh = blockIdx.x >> 3, vg8 = blockIdx.x & 7;
    int kk = threadIdx.x >> 3, vv = vg8 * 8 + (threadIdx.x & 7);
    float S = 0.f;
    for (int c = 0; c < NC; ++c) {
        size_t idx = (size_t)(bh * 32 + c) * 2048 + kk * 64 + vv;
        float P = Pbuf[idx];
        float D = Dbuf[(size_t)(bh * 32 + c) * 32 + kk];
        Sbuf[idx] = S;
        S = D * S + P;
    }
}

// ---------------- GLA phase 3 (qvg stride 3072) ----------------
__global__ __launch_bounds__(256) void gla_phase3(
    const bf16* __restrict__ qvg,
    const float* __restrict__ clbuf, const float* __restrict__ Sbuf,
    const bf16* __restrict__ rmsw, bf16* __restrict__ obuf)
{
    int bh = blockIdx.x, c = blockIdx.y;
    int b = bh >> 4, hh = bh & 15;
    int row0 = b * 2048 + c * CHK;
    __shared__ float qs[CHK][36], ks[CHK][36];
    __shared__ float S0[DK][68];
    __shared__ float Amat[CHK][CHK + 1];
    __shared__ __align__(16) ushort vt[CHK][DV];
    int tid = threadIdx.x;
    {
        int k = tid & 31, i8 = (tid >> 5) * 8;
        #pragma unroll
        for (int u = 0; u < 8; ++u) {
            int i = i8 + u;
            size_t r = (size_t)(row0 + i);
            int col = hh * 32 + k;
            float cl = fmaxf(clbuf[r * 512 + col], -60.f);
            qs[i][k] = b2f(qvg[r * 3072 + col]) * expf(cl) * 0.17677669529663687f;
            ks[i][k] = b2f(qvg[r * 3072 + 512 + col]) * expf(-cl);
        }
    }
    {
        int cc = tid & 7, ii = tid >> 3;
        #pragma unroll
        for (int h = 0; h < 2; ++h) {
            int i = ii + h * 32;
            uint4 val = *(const uint4*)((const ushort*)qvg + (size_t)(row0 + i) * 3072 + 1024 + hh * 64 + cc * 8);
            *(uint4*)&vt[i][cc * 8] = val;
        }
    }
    {
        int kk = tid >> 3, v8 = (tid & 7) * 8;
        const float* Sp = Sbuf + (size_t)(bh * 32 + c) * 2048 + kk * 64 + v8;
        *(f32x4*)&S0[kk][v8]     = *(const f32x4*)Sp;
        *(f32x4*)&S0[kk][v8 + 4] = *(const f32x4*)(Sp + 4);
    }
    __syncthreads();
    int i = tid >> 2, jb = tid & 3;
    for (int jj = 0; jj < 16; ++jj) {
        int j = jb + jj * 4;
        float d = 0.f;
        if (j <= i) {
            const f32x4* qp = (const f32x4*)qs[i];
            const f32x4* kp = (const f32x4*)ks[j];
            #pragma unroll
            for (int q8 = 0; q8 < 8; ++q8) {
                f32x4 a = qp[q8], bq = kp[q8];
                d += a.x * bq.x + a.y * bq.y + a.z * bq.z + a.w * bq.w;
            }
        }
        Amat[i][j] = d;
    }
    __syncthreads();
    float o[16] = {};
    int vv = jb * 16;
    for (int j = 0; j < CHK; ++j) {
        float a = Amat[i][j];
        uint4 r0 = *(const uint4*)&vt[j][vv];
        uint4 r1 = *(const uint4*)&vt[j][vv + 8];
        acc8(a, r0, o);
        acc8(a, r1, o + 8);
    }
    #pragma unroll
    for (int kk = 0; kk < DK; ++kk) {
        float qv = qs[i][kk];
        const f32x4* Sp = (const f32x4*)&S0[kk][vv];
        #pragma unroll
        for (int q4 = 0; q4 < 4; ++q4) {
            f32x4 sv = Sp[q4];
            o[q4 * 4 + 0] += qv * sv.x; o[q4 * 4 + 1] += qv * sv.y;
            o[q4 * 4 + 2] += qv * sv.z; o[q4 * 4 + 3] += qv * sv.w;
        }
    }
    float ss = 0.f;
    #pragma unroll
    for (int u = 0; u < 16; ++u) ss += o[u] * o[u];
    ss += __shfl_xor(ss, 1);
    ss += __shfl_xor(ss, 2);
    float sc = rsqrtf(fmaxf(ss, 0.f) * (1.f / DV) + 1e-5f);
    size_t r = (size_t)(row0 + i);
    #pragma unroll
    for (int u = 0; u < 16; ++u) {
        float g = b2f(qvg[r * 3072 + 2048 + hh * 64 + vv + u]);
        float sw = g / (1.f + expf(-g));
        obuf[r * 1024 + hh * 64 + vv + u] = f2b(clampf(o[u] * sc * b2f(rmsw[vv + u]) * sw, 3e4f));
    }
}

// ---------------- launcher ----------------
extern "C" void kernel_launch(void* const* d_in, const int* in_sizes, int n_in,
                              void* d_out, int out_size, void* d_ws, size_t ws_size,
                              hipStream_t stream) {
    (void)in_sizes; (void)n_in; (void)out_size; (void)ws_size;

    char* ws = (char*)d_ws;
    const size_t MB = 1024 * 1024;
    const size_t KB = 1024;
    bf16*  WqkT = (bf16*)(ws + 0);          // 0-2 MB  (combined [3072][1024] with WvgT)
    bf16*  WkT  = (bf16*)(ws + 1 * MB);
    bf16*  WvgT = (bf16*)(ws + 2 * MB);     // 2-6 MB
    bf16*  WgT  = (bf16*)(ws + 4 * MB);
    bf16*  WoT  = (bf16*)(ws + 6 * MB);     // 6-8
    bf16*  W1T  = (bf16*)(ws + 8 * MB);     // 8-12
    bf16*  W2T  = (bf16*)(ws + 12 * MB);    // 12-16
    bf16*  hbuf = (bf16*)(ws + 16 * MB);    // 16-24 (h, later h2)
    bf16*  qvg  = (bf16*)(ws + 24 * MB);    // 24-48 [4096][3072] (dead after phase3)
    bf16*  gkb  = (bf16*)(ws + 48 * MB);    // 48-52 (dead after phase1)
    float* clbf = (float*)(ws + 52 * MB);   // 52-60 (dead after phase3)
    float* Dbuf = (float*)(ws + 60 * MB);   // 60-61 (dead after scan)
    float* Pbuf = (float*)(ws + 61 * MB);   // 61-69 (dead after scan)
    float* Sbuf = (float*)(ws + 69 * MB);   // 69-77 (dead after phase3)
    bf16*  obuf = (bf16*)(ws + 61 * MB);    // aliases Pbuf (dead)
    float* ybuf = (float*)(ws + 32 * MB);   // 32-48, aliases qvg tail (dead after phase3)
    bf16*  f1   = (bf16*)(ws + 48 * MB);    // 48-64, aliases gkb/clbf/Dbuf/obuf-head (dead)
    bf16*  cx   = (bf16*)(ws + 77 * MB);    // 77-85
    bf16*  clnw = (bf16*)(ws + 85 * MB);
    bf16*  clnb = (bf16*)(ws + 85 * MB + 64 * KB);
    bf16*  cgw1 = (bf16*)(ws + 85 * MB + 128 * KB);
    bf16*  cgw2 = (bf16*)(ws + 85 * MB + 192 * KB);
    bf16*  cgb2 = (bf16*)(ws + 85 * MB + 256 * KB);
    bf16*  crms = (bf16*)(ws + 85 * MB + 320 * KB);
    bf16*  cb1  = (bf16*)(ws + 85 * MB + 384 * KB);
    bf16*  cb2  = (bf16*)(ws + 85 * MB + 448 * KB);
    int*   flag = (int*)(ws + 85 * MB + 512 * KB);

    // 1. detect dtype
    hipLaunchKernelGGL(detect_dtype, dim3(1), dim3(256), 0, stream,
                       (const unsigned int*)d_in[0], flag);

    // 2. canonicalize x + small tensors
    hipLaunchKernelGGL(cvt_to_bf16, dim3(2048), dim3(256), 0, stream,
                       d_in[0], cx, 4194304, flag);
    SmallCvt sc;
    sc.s[0] = d_in[1];  sc.d[0] = clnw; sc.n[0] = 1024;
    sc.s[1] = d_in[2];  sc.d[1] = clnb; sc.n[1] = 1024;
    sc.s[2] = d_in[6];  sc.d[2] = cgw1; sc.n[2] = 16384;
    sc.s[3] = d_in[7];  sc.d[3] = cgw2; sc.n[3] = 8192;
    sc.s[4] = d_in[8];  sc.d[4] = cgb2; sc.n[4] = 512;
    sc.s[5] = d_in[10]; sc.d[5] = crms; sc.n[5] = 64;
    sc.s[6] = d_in[13]; sc.d[6] = cb1;  sc.n[6] = 2048;
    sc.s[7] = d_in[15]; sc.d[7] = cb2;  sc.n[7] = 1024;
    hipLaunchKernelGGL(cvt_small, dim3(64), dim3(256), 0, stream, sc, flag);

    // 3. fused cvt+transpose of the 7 big weights
    dim3 tb(32, 8);
    hipLaunchKernelGGL(transpose_any, dim3(16, 32), tb, 0, stream, d_in[3],  (ushort*)WqkT, 1024, 512, flag);
    hipLaunchKernelGGL(transpose_any, dim3(16, 32), tb, 0, stream, d_in[4],  (ushort*)WkT,  1024, 512, flag);
    hipLaunchKernelGGL(transpose_any, dim3(32, 32), tb, 0, stream, d_in[5],  (ushort*)WvgT, 1024, 1024, flag);
    hipLaunchKernelGGL(transpose_any, dim3(32, 32), tb, 0, stream, d_in[9],  (ushort*)WgT,  1024, 1024, flag);
    hipLaunchKernelGGL(transpose_any, dim3(32, 32), tb, 0, stream, d_in[11], (ushort*)WoT,  1024, 1024, flag);
    hipLaunchKernelGGL(transpose_any, dim3(64, 32), tb, 0, stream, d_in[12], (ushort*)W1T,  1024, 2048, flag);
    hipLaunchKernelGGL(transpose_any, dim3(32, 64), tb, 0, stream, d_in[14], (ushort*)W2T,  2048, 1024, flag);

    // 4. pipeline
    hipLaunchKernelGGL((ln_kernel<bf16>), dim3(BT), dim3(256), 0, stream, cx, clnw, clnb, hbuf);

    // fused q|k|v|g projection: N=3072 (weights contiguous at WqkT)
    hipLaunchKernelGGL((gemm_bt<0>), dim3(32, 48), dim3(256), 0, stream,
                       hbuf, WqkT, (const bf16*)nullptr, (const void*)nullptr, (void*)qvg, BT, 3072, 1024, (const int*)nullptr);
    hipLaunchKernelGGL(gk_kernel, dim3(BT), dim3(256), 0, stream, hbuf, cgw1, cgw2, cgb2, gkb);

    hipLaunchKernelGGL(gla_phase1, dim3(32, 32), dim3(256), 0, stream, gkb, qvg, clbf, Dbuf, Pbuf);
    hipLaunchKernelGGL(gla_scan, dim3(256), dim3(256), 0, stream, Pbuf, Dbuf, Sbuf);
    hipLaunchKernelGGL(gla_phase3, dim3(32, 32), dim3(256), 0, stream, qvg, clbf, Sbuf, crms, obuf);

    hipLaunchKernelGGL((gemm_bt<1>), dim3(32, 16), dim3(256), 0, stream,
                       obuf, WoT, (const bf16*)nullptr, (const void*)cx, (void*)ybuf, BT, 1024, 1024, (const int*)nullptr);
    hipLaunchKernelGGL((ln_kernel<float>), dim3(BT), dim3(256), 0, stream, ybuf, clnw, clnb, hbuf);
    hipLaunchKernelGGL((gemm_bt<2>), dim3(32, 32), dim3(256), 0, stream,
                       hbuf, W1T, cb1, (const void*)nullptr, (void*)f1, BT, 2048, 1024, (const int*)nullptr);
    hipLaunchKernelGGL((gemm_bt<3>), dim3(32, 16), dim3(256), 0, stream,
                       f1, W2T, cb2, (const void*)ybuf, d_out, BT, 1024, 2048, flag);
}